// Round 6
// baseline (241.239 us; speedup 1.0000x reference)
//
#include <hip/hip_runtime.h>
#include <hip/hip_bf16.h>
#include <stdint.h>

#define B_ 2
#define S_ 2048
#define D_ 1024
#define H_ 16
#define DK_ 64

typedef __attribute__((ext_vector_type(4))) float floatx4;
typedef __attribute__((ext_vector_type(8))) short shortx8;
typedef __attribute__((ext_vector_type(4))) short shortx4;
typedef unsigned short ushort_t;

// f32 -> bf16 round-to-nearest-even (used for GEMM outputs)
__device__ inline ushort_t f2bf(float f) {
  union { float f; unsigned u; } v; v.f = f;
  unsigned r = v.u + 0x7FFFu + ((v.u >> 16) & 1u);
  return (ushort_t)(r >> 16);
}

// pack two f32 -> bf16x2 by truncation (1 v_perm); fine for P >= 0 / O
__device__ inline unsigned pack2bf(float lo, float hi) {
  return __builtin_amdgcn_perm(__float_as_uint(hi), __float_as_uint(lo), 0x07060302u);
}

__device__ inline shortx4 mk_sx4(unsigned lo, unsigned hi) {
  union { unsigned u[2]; shortx4 s; } v; v.u[0] = lo; v.u[1] = hi; return v.s;
}

__device__ inline float fast_exp2(float x) {
#if __has_builtin(__builtin_amdgcn_exp2f)
  return __builtin_amdgcn_exp2f(x);
#else
  return __expf(0.69314718056f * x);
#endif
}

__device__ inline void gload_lds16(const void* g, void* l) {
  __builtin_amdgcn_global_load_lds(
      (const __attribute__((address_space(1))) unsigned int*)g,
      (__attribute__((address_space(3))) unsigned int*)l, 16, 0, 0);
}

__device__ inline floatx4 mfma16x16x16bf16(shortx4 a, shortx4 b, floatx4 c) {
#if __has_builtin(__builtin_amdgcn_mfma_f32_16x16x16bf16_1k)
  return __builtin_amdgcn_mfma_f32_16x16x16bf16_1k(a, b, c, 0, 0, 0);
#else
  floatx4 d;
  asm("v_mfma_f32_16x16x16_bf16 %0, %1, %2, %3" : "=v"(d) : "v"(a), "v"(b), "v"(c));
  return d;
#endif
}

// ---------------- fp32 -> bf16 conversion (7 tensors fused) ----------------
struct ConvArgs {
  const float* src[7];
  ushort_t* dst[7];
};

__global__ __launch_bounds__(256) void convert_kernel(ConvArgs a) {
  int blk = blockIdx.x;
  int seg, bis;
  if (blk < 3072) { seg = blk >> 10; bis = blk & 1023; }
  else { int bb = blk - 3072; seg = 3 + (bb >> 8); bis = bb & 255; }
  const float4* src = (const float4*)(a.src[seg]) + (size_t)bis * 1024;
  ushort4* dst = (ushort4*)(a.dst[seg]) + (size_t)bis * 1024;
#pragma unroll
  for (int i = 0; i < 4; ++i) {
    int idx = i * 256 + threadIdx.x;
    float4 v = src[idx];
    ushort4 o;
    o.x = f2bf(v.x); o.y = f2bf(v.y); o.z = f2bf(v.z); o.w = f2bf(v.w);
    dst[idx] = o;
  }
}

// ---------------- GEMM: C[m][n] = (sum_k A[m][k]*W[n][k] + bias[n])*scl ----
// TM x 128 tile, BK=32, double-buffered LDS with global_load_lds prefetch.
// 4 waves in 2x2 layout: wave tile (TM/2) x 64.
// OUTMODE: 0 = bf16 row-major, 1 = f32 row-major, 2 = bf16 V-transpose
// (out[(b*1024+n)*2048 + s], m = b*2048+s; fuses the attention V^T layout).
template <int TM, int OUTMODE>
__device__ inline void gemm_bt_core(const ushort_t* __restrict__ A,
                                    const ushort_t* __restrict__ W,
                                    const float* __restrict__ bias,
                                    float scl,
                                    void* __restrict__ outp,
                                    int m0, int n0, int N, int K) {
  constexpr int LDSU = (TM + 128) * 32;  // ushorts per buffer
  constexpr int GA = TM / 16;            // A gloads (16 rows each)
  constexpr int GW = (GA + 8) / 4;       // gloads per wave
  constexpr int MI = TM / 32;            // m-frags per wave
  __shared__ ushort_t smem[2][LDSU];
  const int tid = threadIdx.x;
  const int wave = tid >> 6;
  const int lane = tid & 63;
  const int quad = lane >> 4;
  const int l16 = lane & 15;
  const int wm = (wave >> 1) * (TM / 2);
  const int wn = (wave & 1) * 64;

  floatx4 acc[MI][4] = {};

  // staging: gload g covers 16 rows; lane -> row lane>>2, col (lane&3)*8
  const ushort_t* gsrc[GW];
  int ldst[GW];
#pragma unroll
  for (int i = 0; i < GW; ++i) {
    int g = wave * GW + i;
    int row = lane >> 2;
    int col = (lane & 3) * 8;
    if (g < GA) {
      gsrc[i] = A + (size_t)(m0 + g * 16 + row) * K + col;
      ldst[i] = g * 512;
    } else {
      gsrc[i] = W + (size_t)(n0 + (g - GA) * 16 + row) * K + col;
      ldst[i] = TM * 32 + (g - GA) * 512;
    }
  }

#pragma unroll
  for (int i = 0; i < GW; ++i) gload_lds16(gsrc[i], &smem[0][ldst[i]]);

  const int niter = K >> 5;
  for (int j = 0; j < niter; ++j) {
    __syncthreads();
    if (j + 1 < niter) {
      const int ko = (j + 1) * 32;
      ushort_t* bufn = smem[(j + 1) & 1];
#pragma unroll
      for (int i = 0; i < GW; ++i) gload_lds16(gsrc[i] + ko, bufn + ldst[i]);
    }
    const ushort_t* aT = smem[j & 1];
    const ushort_t* bT = smem[j & 1] + TM * 32;
    shortx8 af[MI], bf[4];
#pragma unroll
    for (int mi = 0; mi < MI; ++mi)
      af[mi] = *(const shortx8*)(aT + (wm + mi * 16 + l16) * 32 + quad * 8);
#pragma unroll
    for (int ni = 0; ni < 4; ++ni)
      bf[ni] = *(const shortx8*)(bT + (wn + ni * 16 + l16) * 32 + quad * 8);
#pragma unroll
    for (int mi = 0; mi < MI; ++mi)
#pragma unroll
      for (int ni = 0; ni < 4; ++ni)
        acc[mi][ni] = __builtin_amdgcn_mfma_f32_16x16x32_bf16(af[mi], bf[ni], acc[mi][ni], 0, 0, 0);
  }

  // epilogue: C/D layout col=lane&15, row=quad*4+r
#pragma unroll
  for (int ni = 0; ni < 4; ++ni) {
    int n = n0 + wn + ni * 16 + l16;
    float bv = bias[n];
#pragma unroll
    for (int mi = 0; mi < MI; ++mi) {
      if (OUTMODE == 2) {
        int m = m0 + wm + mi * 16 + quad * 4;
        int b = m >> 11, s = m & 2047;
        ushort_t* dst = (ushort_t*)outp + (((size_t)(b * 1024 + n)) << 11) + s;
        unsigned lo = (unsigned)f2bf(acc[mi][ni][0] + bv) |
                      ((unsigned)f2bf(acc[mi][ni][1] + bv) << 16);
        unsigned hi = (unsigned)f2bf(acc[mi][ni][2] + bv) |
                      ((unsigned)f2bf(acc[mi][ni][3] + bv) << 16);
        *(unsigned*)(dst) = lo;
        *(unsigned*)(dst + 2) = hi;
      } else {
#pragma unroll
        for (int r = 0; r < 4; ++r) {
          int m = m0 + wm + mi * 16 + quad * 4 + r;
          float v = (acc[mi][ni][r] + bv) * scl;
          if (OUTMODE == 1) ((float*)outp)[(size_t)m * N + n] = v;
          else ((ushort_t*)outp)[(size_t)m * N + n] = f2bf(v);
        }
      }
    }
  }
}

struct QkvArgs {
  const ushort_t* A[3];
  const ushort_t* W[3];
  const float* bias[3];
  ushort_t* out[3];
  float scale[3];
};

// grid (8,32,3); XCD swizzle: flat%8 == blockIdx.x -> make x the m-group so
// XCD c's L2 working set = 4 A-tiles (1MB) + full W (2MB) < 4MB.
// z==2 (V) writes the transposed layout consumed by attention (fused vtrans).
__global__ __launch_bounds__(256) void gemm_qkv_kernel(QkvArgs a) {
  int z = blockIdx.z;
  int m0 = (blockIdx.x * 4 + (blockIdx.y >> 3)) * 128;
  int n0 = (blockIdx.y & 7) * 128;
  if (z == 2)
    gemm_bt_core<128, 2>(a.A[2], a.W[2], a.bias[2], 1.0f, a.out[2], m0, n0, D_, D_);
  else
    gemm_bt_core<128, 0>(a.A[z], a.W[z], a.bias[z], a.scale[z], a.out[z], m0, n0, D_, D_);
}

// grid (8,64); 64x128 tiles (2 blocks/CU), same swizzle principle.
__global__ __launch_bounds__(256) void gemm_out_kernel(const ushort_t* __restrict__ A,
                                                       const ushort_t* __restrict__ W,
                                                       const float* __restrict__ bias,
                                                       float* __restrict__ out) {
  int m0 = (blockIdx.x * 8 + (blockIdx.y >> 3)) * 64;
  int n0 = (blockIdx.y & 7) * 128;
  gemm_bt_core<64, 1>(A, W, bias, 1.0f, out, m0, n0, D_, D_);
}

// ---------------- flash attention (causal), pipelined, no-max softmax ------
// 1D grid of 512; id<256 -> (b=0, qt=15-(id>>4)), id>=256 -> (b=1, qt=id>>4).
// With round-robin block->CU dispatch, CU c gets blocks c and c+256 whose
// iteration counts sum to a CONSTANT 36 -> balanced makespan (vs 64 when both
// blocks on a CU had the same qt).
__global__ __launch_bounds__(256, 2) void attn_kernel(const ushort_t* __restrict__ Qp,
                                                      const ushort_t* __restrict__ Kp,
                                                      const ushort_t* __restrict__ Vt,
                                                      ushort_t* __restrict__ O) {
  const int id = blockIdx.x;
  const int h = id & 15;
  const int qq = (id & 255) >> 4;
  const int b = id >> 8;
  const int qt = b ? qq : 15 - qq;
  const int q0 = qt * 128;
  const int tid = threadIdx.x;
  const int wave = tid >> 6;
  const int lane = tid & 63;
  const int quad = lane >> 4;
  const int l16 = lane & 15;

  __shared__ ushort_t smem[2][8192];  // per buf: k tile [64][64] | v^T tile [64][64]

  const size_t hoff = (size_t)h * DK_;

  // Q B-frags: lane holds Q[q=l16][d=ks*32+quad*8+i] (already exp2-scaled)
  shortx8 qf[2][2];
#pragma unroll
  for (int grp = 0; grp < 2; ++grp) {
    const ushort_t* qrow = Qp + ((size_t)b * S_ + q0 + wave * 32 + grp * 16 + l16) * D_ + hoff;
#pragma unroll
    for (int ks = 0; ks < 2; ++ks)
      qf[grp][ks] = *(const shortx8*)(qrow + ks * 32 + quad * 8);
  }

  // staging: wave w stages K rows [w*16,+16) and V^T rows [w*16,+16)
  const int r8 = lane >> 3;               // row within 8-row chunk
  const int jj8 = ((lane & 7) ^ r8) * 8;  // swizzled 16B chunk, ushort units
  const ushort_t* kb[2];
  const ushort_t* vb[2];
#pragma unroll
  for (int g = 0; g < 2; ++g) {
    int r = wave * 16 + g * 8 + r8;
    kb[g] = Kp + ((size_t)b * S_ + r) * D_ + hoff + jj8;
    vb[g] = Vt + ((size_t)(b * H_ + h) * 64 + r) * S_ + jj8;
  }
  const int ldsrow = (wave * 16) * 64;

  floatx4 oacc[2][4] = {};
  float l_run[2] = {0.f, 0.f};
  const int nj = 2 * qt + 2;
  const int qwave_max = q0 + wave * 32 + 31;

  // preload tile 0 into buffer 0
#pragma unroll
  for (int g = 0; g < 2; ++g) {
    gload_lds16(kb[g], &smem[0][ldsrow + g * 512]);
    gload_lds16(vb[g], &smem[0][4096 + ldsrow + g * 512]);
  }

  for (int j = 0; j < nj; ++j) {
    __syncthreads();
    if (j + 1 < nj) {
      ushort_t* bufn = smem[(j + 1) & 1];
      const size_t ko = (size_t)(j + 1) * 64 * D_;
      const int vo = (j + 1) * 64;
#pragma unroll
      for (int g = 0; g < 2; ++g) {
        gload_lds16(kb[g] + ko, bufn + ldsrow + g * 512);
        gload_lds16(vb[g] + vo, bufn + 4096 + ldsrow + g * 512);
      }
    }
    if ((j << 6) > qwave_max) continue;  // tile fully masked for this wave
    const ushort_t* k_lds = smem[j & 1];
    const ushort_t* v_lds = smem[j & 1] + 4096;

    // S^T[kk=kkb*16+quad*4+r][q=l16] per group
    floatx4 sacc[2][4];
#pragma unroll
    for (int kkb = 0; kkb < 4; ++kkb) {
      const ushort_t* krow = k_lds + (kkb * 16 + l16) * 64;
      shortx8 af0 = *(const shortx8*)(krow + (quad ^ (l16 & 7)) * 8);
      shortx8 af1 = *(const shortx8*)(krow + ((4 | quad) ^ (l16 & 7)) * 8);
#pragma unroll
      for (int grp = 0; grp < 2; ++grp) {
        floatx4 acc = {0.f, 0.f, 0.f, 0.f};
        acc = __builtin_amdgcn_mfma_f32_16x16x32_bf16(af0, qf[grp][0], acc, 0, 0, 0);
        acc = __builtin_amdgcn_mfma_f32_16x16x32_bf16(af1, qf[grp][1], acc, 0, 0, 0);
        sacc[grp][kkb] = acc;
      }
    }
    // diagonal masking (global indices)
#pragma unroll
    for (int grp = 0; grp < 2; ++grp) {
      const int qg = q0 + wave * 32 + grp * 16 + l16;
      if ((j << 6) + 63 > q0 + wave * 32 + grp * 16) {
#pragma unroll
        for (int kkb = 0; kkb < 4; ++kkb)
#pragma unroll
          for (int r = 0; r < 4; ++r)
            if ((j << 6) + kkb * 16 + quad * 4 + r > qg) sacc[grp][kkb][r] = -3.0e38f;
      }
    }

    // no-max softmax: p = exp2(s); per-lane partial l
    shortx4 pf[2][4];
#pragma unroll
    for (int grp = 0; grp < 2; ++grp) {
      float psum = 0.f;
#pragma unroll
      for (int kkb = 0; kkb < 4; ++kkb) {
        float p0 = fast_exp2(sacc[grp][kkb][0]);
        float p1 = fast_exp2(sacc[grp][kkb][1]);
        float p2 = fast_exp2(sacc[grp][kkb][2]);
        float p3 = fast_exp2(sacc[grp][kkb][3]);
        psum += (p0 + p1) + (p2 + p3);
        pf[grp][kkb] = mk_sx4(pack2bf(p0, p1), pack2bf(p2, p3));
      }
      l_run[grp] += psum;
    }

    // PV: oacc[grp][db] += V^T[d=db*16+..][kk block] * P^T
#pragma unroll
    for (int kkb = 0; kkb < 4; ++kkb) {
      const int jj = ((2 * kkb + (quad >> 1)) ^ (l16 & 7)) * 8 + (quad & 1) * 4;
#pragma unroll
      for (int db = 0; db < 4; ++db) {
        shortx4 vf = *(const shortx4*)(v_lds + (db * 16 + l16) * 64 + jj);
        oacc[0][db] = mfma16x16x16bf16(vf, pf[0][kkb], oacc[0][db]);
        oacc[1][db] = mfma16x16x16bf16(vf, pf[1][kkb], oacc[1][db]);
      }
    }
  }

  // epilogue: reduce l across quads, normalize, pack, transpose via LDS
  __syncthreads();
  ushort_t* sm = &smem[0][0];
#pragma unroll
  for (int grp = 0; grp < 2; ++grp) {
    float l0 = l_run[grp];
    l0 += __shfl_xor(l0, 16);
    l0 += __shfl_xor(l0, 32);
    float inv_l = 1.0f / l0;
    int row = wave * 32 + grp * 16 + l16;
#pragma unroll
    for (int db = 0; db < 4; ++db) {
#pragma unroll
      for (int rr = 0; rr < 2; ++rr) {
        unsigned pk = pack2bf(oacc[grp][db][rr * 2] * inv_l, oacc[grp][db][rr * 2 + 1] * inv_l);
        *(unsigned*)(sm + row * 72 + db * 16 + quad * 4 + rr * 2) = pk;
      }
    }
  }
  __syncthreads();
  {
    int r = tid >> 1, c = (tid & 1) * 32;
    const ushort_t* src = sm + r * 72 + c;
    ushort_t* dst = O + ((size_t)b * S_ + q0 + r) * D_ + hoff + c;
    uint4 v0 = *(const uint4*)(src);
    uint4 v1 = *(const uint4*)(src + 8);
    uint4 v2 = *(const uint4*)(src + 16);
    uint4 v3 = *(const uint4*)(src + 24);
    *(uint4*)(dst) = v0;
    *(uint4*)(dst + 8) = v1;
    *(uint4*)(dst + 16) = v2;
    *(uint4*)(dst + 24) = v3;
  }
}

// ---------------------------------------------------------------------------
extern "C" void kernel_launch(void* const* d_in, const int* in_sizes, int n_in,
                              void* d_out, int out_size, void* d_ws, size_t ws_size,
                              hipStream_t stream) {
  (void)in_sizes; (void)n_in; (void)out_size; (void)ws_size;
  char* ws = (char*)d_ws;
  ushort_t* xq = (ushort_t*)(ws + 0);
  ushort_t* xk = (ushort_t*)(ws + 8388608);
  ushort_t* xv = (ushort_t*)(ws + 16777216);
  ushort_t* wq = (ushort_t*)(ws + 25165824);
  ushort_t* wk = (ushort_t*)(ws + 27262976);
  ushort_t* wv = (ushort_t*)(ws + 29360128);
  ushort_t* wo = (ushort_t*)(ws + 31457280);
  ushort_t* Qp = (ushort_t*)(ws + 33554432);
  ushort_t* Kp = (ushort_t*)(ws + 41943040);
  ushort_t* Vt = (ushort_t*)(ws + 50331648);  // V GEMM writes transposed here
  ushort_t* O = xq;   // xq dead after QKV GEMM

  ConvArgs ca;
  ca.src[0] = (const float*)d_in[0];  ca.dst[0] = xq;
  ca.src[1] = (const float*)d_in[1];  ca.dst[1] = xk;
  ca.src[2] = (const float*)d_in[2];  ca.dst[2] = xv;
  ca.src[3] = (const float*)d_in[4];  ca.dst[3] = wq;
  ca.src[4] = (const float*)d_in[6];  ca.dst[4] = wk;
  ca.src[5] = (const float*)d_in[8];  ca.dst[5] = wv;
  ca.src[6] = (const float*)d_in[10]; ca.dst[6] = wo;
  convert_kernel<<<dim3(4096), dim3(256), 0, stream>>>(ca);

  QkvArgs qa;
  qa.A[0] = xq; qa.W[0] = wq; qa.bias[0] = (const float*)d_in[5]; qa.out[0] = Qp;
  qa.A[1] = xk; qa.W[1] = wk; qa.bias[1] = (const float*)d_in[7]; qa.out[1] = Kp;
  qa.A[2] = xv; qa.W[2] = wv; qa.bias[2] = (const float*)d_in[9]; qa.out[2] = Vt;
  qa.scale[0] = 0.125f * 1.44269504089f;  // fold 1/sqrt(dk) * log2(e) into Q
  qa.scale[1] = 1.0f;
  qa.scale[2] = 1.0f;
  gemm_qkv_kernel<<<dim3(8, 32, 3), dim3(256), 0, stream>>>(qa);

  attn_kernel<<<dim3(512), dim3(256), 0, stream>>>(Qp, Kp, Vt, O);

  gemm_out_kernel<<<dim3(8, 64, 1), dim3(256), 0, stream>>>(
      O, wo, (const float*)d_in[11], (float*)d_out);
}

// Round 7
// 232.594 us; speedup vs baseline: 1.0372x; 1.0372x over previous
//
#include <hip/hip_runtime.h>
#include <hip/hip_bf16.h>
#include <stdint.h>

#define B_ 2
#define S_ 2048
#define D_ 1024
#define H_ 16
#define DK_ 64

typedef __attribute__((ext_vector_type(4))) float floatx4;
typedef __attribute__((ext_vector_type(8))) short shortx8;
typedef __attribute__((ext_vector_type(4))) short shortx4;
typedef unsigned short ushort_t;

// f32 -> bf16 round-to-nearest-even (used for GEMM outputs)
__device__ inline ushort_t f2bf(float f) {
  union { float f; unsigned u; } v; v.f = f;
  unsigned r = v.u + 0x7FFFu + ((v.u >> 16) & 1u);
  return (ushort_t)(r >> 16);
}

// pack two f32 -> bf16x2 by truncation (1 v_perm); fine for P >= 0 / O
__device__ inline unsigned pack2bf(float lo, float hi) {
  return __builtin_amdgcn_perm(__float_as_uint(hi), __float_as_uint(lo), 0x07060302u);
}

__device__ inline shortx4 mk_sx4(unsigned lo, unsigned hi) {
  union { unsigned u[2]; shortx4 s; } v; v.u[0] = lo; v.u[1] = hi; return v.s;
}

__device__ inline float fast_exp2(float x) {
#if __has_builtin(__builtin_amdgcn_exp2f)
  return __builtin_amdgcn_exp2f(x);
#else
  return __expf(0.69314718056f * x);
#endif
}

__device__ inline void gload_lds16(const void* g, void* l) {
  __builtin_amdgcn_global_load_lds(
      (const __attribute__((address_space(1))) unsigned int*)g,
      (__attribute__((address_space(3))) unsigned int*)l, 16, 0, 0);
}

__device__ inline floatx4 mfma16x16x16bf16(shortx4 a, shortx4 b, floatx4 c) {
#if __has_builtin(__builtin_amdgcn_mfma_f32_16x16x16bf16_1k)
  return __builtin_amdgcn_mfma_f32_16x16x16bf16_1k(a, b, c, 0, 0, 0);
#else
  floatx4 d;
  asm("v_mfma_f32_16x16x16_bf16 %0, %1, %2, %3" : "=v"(d) : "v"(a), "v"(b), "v"(c));
  return d;
#endif
}

// ---------------- fp32 -> bf16 conversion (7 tensors fused) ----------------
struct ConvArgs {
  const float* src[7];
  ushort_t* dst[7];
};

__global__ __launch_bounds__(256) void convert_kernel(ConvArgs a) {
  int blk = blockIdx.x;
  int seg, bis;
  if (blk < 3072) { seg = blk >> 10; bis = blk & 1023; }
  else { int bb = blk - 3072; seg = 3 + (bb >> 8); bis = bb & 255; }
  const float4* src = (const float4*)(a.src[seg]) + (size_t)bis * 1024;
  ushort4* dst = (ushort4*)(a.dst[seg]) + (size_t)bis * 1024;
#pragma unroll
  for (int i = 0; i < 4; ++i) {
    int idx = i * 256 + threadIdx.x;
    float4 v = src[idx];
    ushort4 o;
    o.x = f2bf(v.x); o.y = f2bf(v.y); o.z = f2bf(v.z); o.w = f2bf(v.w);
    dst[idx] = o;
  }
}

// ---------------- GEMM: C[m][n] = (sum_k A[m][k]*W[n][k] + bias[n])*scl ----
// TM x 128 tile, BK=32, double-buffered LDS with global_load_lds prefetch.
// 4 waves in 2x2 layout: wave tile (TM/2) x 64.
// outmode (RUNTIME arg -- one template instantiation => one LDS allocation;
// two instantiations in one kernel would DOUBLE the static LDS and halve
// occupancy, which cost 8 us in round 6):
//   0 = bf16 row-major, 1 = f32 row-major,
//   2 = bf16 V-transpose out[(b*1024+n)*2048 + s], m = b*2048+s.
template <int TM>
__device__ inline void gemm_bt_core(const ushort_t* __restrict__ A,
                                    const ushort_t* __restrict__ W,
                                    const float* __restrict__ bias,
                                    float scl,
                                    void* __restrict__ outp,
                                    int m0, int n0, int N, int K, int outmode) {
  constexpr int LDSU = (TM + 128) * 32;  // ushorts per buffer
  constexpr int GA = TM / 16;            // A gloads (16 rows each)
  constexpr int GW = (GA + 8) / 4;       // gloads per wave
  constexpr int MI = TM / 32;            // m-frags per wave
  __shared__ ushort_t smem[2][LDSU];
  const int tid = threadIdx.x;
  const int wave = tid >> 6;
  const int lane = tid & 63;
  const int quad = lane >> 4;
  const int l16 = lane & 15;
  const int wm = (wave >> 1) * (TM / 2);
  const int wn = (wave & 1) * 64;

  floatx4 acc[MI][4] = {};

  // staging: gload g covers 16 rows; lane -> row lane>>2, col (lane&3)*8
  const ushort_t* gsrc[GW];
  int ldst[GW];
#pragma unroll
  for (int i = 0; i < GW; ++i) {
    int g = wave * GW + i;
    int row = lane >> 2;
    int col = (lane & 3) * 8;
    if (g < GA) {
      gsrc[i] = A + (size_t)(m0 + g * 16 + row) * K + col;
      ldst[i] = g * 512;
    } else {
      gsrc[i] = W + (size_t)(n0 + (g - GA) * 16 + row) * K + col;
      ldst[i] = TM * 32 + (g - GA) * 512;
    }
  }

#pragma unroll
  for (int i = 0; i < GW; ++i) gload_lds16(gsrc[i], &smem[0][ldst[i]]);

  const int niter = K >> 5;
  for (int j = 0; j < niter; ++j) {
    __syncthreads();
    if (j + 1 < niter) {
      const int ko = (j + 1) * 32;
      ushort_t* bufn = smem[(j + 1) & 1];
#pragma unroll
      for (int i = 0; i < GW; ++i) gload_lds16(gsrc[i] + ko, bufn + ldst[i]);
    }
    const ushort_t* aT = smem[j & 1];
    const ushort_t* bT = smem[j & 1] + TM * 32;
    shortx8 af[MI], bf[4];
#pragma unroll
    for (int mi = 0; mi < MI; ++mi)
      af[mi] = *(const shortx8*)(aT + (wm + mi * 16 + l16) * 32 + quad * 8);
#pragma unroll
    for (int ni = 0; ni < 4; ++ni)
      bf[ni] = *(const shortx8*)(bT + (wn + ni * 16 + l16) * 32 + quad * 8);
#pragma unroll
    for (int mi = 0; mi < MI; ++mi)
#pragma unroll
      for (int ni = 0; ni < 4; ++ni)
        acc[mi][ni] = __builtin_amdgcn_mfma_f32_16x16x32_bf16(af[mi], bf[ni], acc[mi][ni], 0, 0, 0);
  }

  // epilogue: C/D layout col=lane&15, row=quad*4+r
#pragma unroll
  for (int ni = 0; ni < 4; ++ni) {
    int n = n0 + wn + ni * 16 + l16;
    float bv = bias[n];
#pragma unroll
    for (int mi = 0; mi < MI; ++mi) {
      if (outmode == 2) {
        int m = m0 + wm + mi * 16 + quad * 4;
        int b = m >> 11, s = m & 2047;
        ushort_t* dst = (ushort_t*)outp + (((size_t)(b * 1024 + n)) << 11) + s;
        uint2 pk;
        pk.x = (unsigned)f2bf(acc[mi][ni][0] + bv) |
               ((unsigned)f2bf(acc[mi][ni][1] + bv) << 16);
        pk.y = (unsigned)f2bf(acc[mi][ni][2] + bv) |
               ((unsigned)f2bf(acc[mi][ni][3] + bv) << 16);
        *(uint2*)(dst) = pk;  // single 8B store (8B-aligned: s = quad*4)
      } else {
#pragma unroll
        for (int r = 0; r < 4; ++r) {
          int m = m0 + wm + mi * 16 + quad * 4 + r;
          float v = (acc[mi][ni][r] + bv) * scl;
          if (outmode == 1) ((float*)outp)[(size_t)m * N + n] = v;
          else ((ushort_t*)outp)[(size_t)m * N + n] = f2bf(v);
        }
      }
    }
  }
}

struct QkvArgs {
  const ushort_t* A[3];
  const ushort_t* W[3];
  const float* bias[3];
  ushort_t* out[3];
  float scale[3];
};

// grid (8,32,3); XCD swizzle: flat%8 == blockIdx.x -> make x the m-group so
// XCD c's L2 working set = 4 A-tiles (1MB) + full W (2MB) < 4MB.
// z==2 (V) writes the transposed layout consumed by attention (fused vtrans).
__global__ __launch_bounds__(256) void gemm_qkv_kernel(QkvArgs a) {
  int z = blockIdx.z;
  int m0 = (blockIdx.x * 4 + (blockIdx.y >> 3)) * 128;
  int n0 = (blockIdx.y & 7) * 128;
  gemm_bt_core<128>(a.A[z], a.W[z], a.bias[z], a.scale[z], a.out[z],
                    m0, n0, D_, D_, z == 2 ? 2 : 0);
}

// grid (8,64); 64x128 tiles (2 blocks/CU), same swizzle principle.
__global__ __launch_bounds__(256) void gemm_out_kernel(const ushort_t* __restrict__ A,
                                                       const ushort_t* __restrict__ W,
                                                       const float* __restrict__ bias,
                                                       float* __restrict__ out) {
  int m0 = (blockIdx.x * 8 + (blockIdx.y >> 3)) * 64;
  int n0 = (blockIdx.y & 7) * 128;
  gemm_bt_core<64>(A, W, bias, 1.0f, out, m0, n0, D_, D_, 1);
}

// ---------------- flash attention (causal), pipelined, no-max softmax ------
// 1D grid of 512; id<256 -> (b=0, qt=15-(id>>4)), id>=256 -> (b=1, qt=id>>4).
// With round-robin block->CU dispatch, CU c gets blocks c and c+256 whose
// iteration counts sum to a CONSTANT 36 -> balanced makespan.
__global__ __launch_bounds__(256, 2) void attn_kernel(const ushort_t* __restrict__ Qp,
                                                      const ushort_t* __restrict__ Kp,
                                                      const ushort_t* __restrict__ Vt,
                                                      ushort_t* __restrict__ O) {
  const int id = blockIdx.x;
  const int h = id & 15;
  const int qq = (id & 255) >> 4;
  const int b = id >> 8;
  const int qt = b ? qq : 15 - qq;
  const int q0 = qt * 128;
  const int tid = threadIdx.x;
  const int wave = tid >> 6;
  const int lane = tid & 63;
  const int quad = lane >> 4;
  const int l16 = lane & 15;

  __shared__ ushort_t smem[2][8192];  // per buf: k tile [64][64] | v^T tile [64][64]

  const size_t hoff = (size_t)h * DK_;

  // Q B-frags: lane holds Q[q=l16][d=ks*32+quad*8+i] (already exp2-scaled)
  shortx8 qf[2][2];
#pragma unroll
  for (int grp = 0; grp < 2; ++grp) {
    const ushort_t* qrow = Qp + ((size_t)b * S_ + q0 + wave * 32 + grp * 16 + l16) * D_ + hoff;
#pragma unroll
    for (int ks = 0; ks < 2; ++ks)
      qf[grp][ks] = *(const shortx8*)(qrow + ks * 32 + quad * 8);
  }

  // staging: wave w stages K rows [w*16,+16) and V^T rows [w*16,+16)
  const int r8 = lane >> 3;               // row within 8-row chunk
  const int jj8 = ((lane & 7) ^ r8) * 8;  // swizzled 16B chunk, ushort units
  const ushort_t* kb[2];
  const ushort_t* vb[2];
#pragma unroll
  for (int g = 0; g < 2; ++g) {
    int r = wave * 16 + g * 8 + r8;
    kb[g] = Kp + ((size_t)b * S_ + r) * D_ + hoff + jj8;
    vb[g] = Vt + ((size_t)(b * H_ + h) * 64 + r) * S_ + jj8;
  }
  const int ldsrow = (wave * 16) * 64;

  floatx4 oacc[2][4] = {};
  float l_run[2] = {0.f, 0.f};
  const int nj = 2 * qt + 2;
  const int qwave_max = q0 + wave * 32 + 31;

  // preload tile 0 into buffer 0
#pragma unroll
  for (int g = 0; g < 2; ++g) {
    gload_lds16(kb[g], &smem[0][ldsrow + g * 512]);
    gload_lds16(vb[g], &smem[0][4096 + ldsrow + g * 512]);
  }

  for (int j = 0; j < nj; ++j) {
    __syncthreads();
    if (j + 1 < nj) {
      ushort_t* bufn = smem[(j + 1) & 1];
      const size_t ko = (size_t)(j + 1) * 64 * D_;
      const int vo = (j + 1) * 64;
#pragma unroll
      for (int g = 0; g < 2; ++g) {
        gload_lds16(kb[g] + ko, bufn + ldsrow + g * 512);
        gload_lds16(vb[g] + vo, bufn + 4096 + ldsrow + g * 512);
      }
    }
    if ((j << 6) > qwave_max) continue;  // tile fully masked for this wave
    const ushort_t* k_lds = smem[j & 1];
    const ushort_t* v_lds = smem[j & 1] + 4096;

    // S^T[kk=kkb*16+quad*4+r][q=l16] per group
    floatx4 sacc[2][4];
#pragma unroll
    for (int kkb = 0; kkb < 4; ++kkb) {
      const ushort_t* krow = k_lds + (kkb * 16 + l16) * 64;
      shortx8 af0 = *(const shortx8*)(krow + (quad ^ (l16 & 7)) * 8);
      shortx8 af1 = *(const shortx8*)(krow + ((4 | quad) ^ (l16 & 7)) * 8);
#pragma unroll
      for (int grp = 0; grp < 2; ++grp) {
        floatx4 acc = {0.f, 0.f, 0.f, 0.f};
        acc = __builtin_amdgcn_mfma_f32_16x16x32_bf16(af0, qf[grp][0], acc, 0, 0, 0);
        acc = __builtin_amdgcn_mfma_f32_16x16x32_bf16(af1, qf[grp][1], acc, 0, 0, 0);
        sacc[grp][kkb] = acc;
      }
    }
    // diagonal masking (global indices)
#pragma unroll
    for (int grp = 0; grp < 2; ++grp) {
      const int qg = q0 + wave * 32 + grp * 16 + l16;
      if ((j << 6) + 63 > q0 + wave * 32 + grp * 16) {
#pragma unroll
        for (int kkb = 0; kkb < 4; ++kkb)
#pragma unroll
          for (int r = 0; r < 4; ++r)
            if ((j << 6) + kkb * 16 + quad * 4 + r > qg) sacc[grp][kkb][r] = -3.0e38f;
      }
    }

    // no-max softmax: p = exp2(s); per-lane partial l
    shortx4 pf[2][4];
#pragma unroll
    for (int grp = 0; grp < 2; ++grp) {
      float psum = 0.f;
#pragma unroll
      for (int kkb = 0; kkb < 4; ++kkb) {
        float p0 = fast_exp2(sacc[grp][kkb][0]);
        float p1 = fast_exp2(sacc[grp][kkb][1]);
        float p2 = fast_exp2(sacc[grp][kkb][2]);
        float p3 = fast_exp2(sacc[grp][kkb][3]);
        psum += (p0 + p1) + (p2 + p3);
        pf[grp][kkb] = mk_sx4(pack2bf(p0, p1), pack2bf(p2, p3));
      }
      l_run[grp] += psum;
    }

    // PV: oacc[grp][db] += V^T[d=db*16+..][kk block] * P^T
#pragma unroll
    for (int kkb = 0; kkb < 4; ++kkb) {
      const int jj = ((2 * kkb + (quad >> 1)) ^ (l16 & 7)) * 8 + (quad & 1) * 4;
#pragma unroll
      for (int db = 0; db < 4; ++db) {
        shortx4 vf = *(const shortx4*)(v_lds + (db * 16 + l16) * 64 + jj);
        oacc[0][db] = mfma16x16x16bf16(vf, pf[0][kkb], oacc[0][db]);
        oacc[1][db] = mfma16x16x16bf16(vf, pf[1][kkb], oacc[1][db]);
      }
    }
  }

  // epilogue: reduce l across quads, normalize, pack, transpose via LDS
  __syncthreads();
  ushort_t* sm = &smem[0][0];
#pragma unroll
  for (int grp = 0; grp < 2; ++grp) {
    float l0 = l_run[grp];
    l0 += __shfl_xor(l0, 16);
    l0 += __shfl_xor(l0, 32);
    float inv_l = 1.0f / l0;
    int row = wave * 32 + grp * 16 + l16;
#pragma unroll
    for (int db = 0; db < 4; ++db) {
#pragma unroll
      for (int rr = 0; rr < 2; ++rr) {
        unsigned pk = pack2bf(oacc[grp][db][rr * 2] * inv_l, oacc[grp][db][rr * 2 + 1] * inv_l);
        *(unsigned*)(sm + row * 72 + db * 16 + quad * 4 + rr * 2) = pk;
      }
    }
  }
  __syncthreads();
  {
    int r = tid >> 1, c = (tid & 1) * 32;
    const ushort_t* src = sm + r * 72 + c;
    ushort_t* dst = O + ((size_t)b * S_ + q0 + r) * D_ + hoff + c;
    uint4 v0 = *(const uint4*)(src);
    uint4 v1 = *(const uint4*)(src + 8);
    uint4 v2 = *(const uint4*)(src + 16);
    uint4 v3 = *(const uint4*)(src + 24);
    *(uint4*)(dst) = v0;
    *(uint4*)(dst + 8) = v1;
    *(uint4*)(dst + 16) = v2;
    *(uint4*)(dst + 24) = v3;
  }
}

// ---------------------------------------------------------------------------
extern "C" void kernel_launch(void* const* d_in, const int* in_sizes, int n_in,
                              void* d_out, int out_size, void* d_ws, size_t ws_size,
                              hipStream_t stream) {
  (void)in_sizes; (void)n_in; (void)out_size; (void)ws_size;
  char* ws = (char*)d_ws;
  ushort_t* xq = (ushort_t*)(ws + 0);
  ushort_t* xk = (ushort_t*)(ws + 8388608);
  ushort_t* xv = (ushort_t*)(ws + 16777216);
  ushort_t* wq = (ushort_t*)(ws + 25165824);
  ushort_t* wk = (ushort_t*)(ws + 27262976);
  ushort_t* wv = (ushort_t*)(ws + 29360128);
  ushort_t* wo = (ushort_t*)(ws + 31457280);
  ushort_t* Qp = (ushort_t*)(ws + 33554432);
  ushort_t* Kp = (ushort_t*)(ws + 41943040);
  ushort_t* Vt = (ushort_t*)(ws + 50331648);  // V GEMM writes transposed here
  ushort_t* O = xq;   // xq dead after QKV GEMM

  ConvArgs ca;
  ca.src[0] = (const float*)d_in[0];  ca.dst[0] = xq;
  ca.src[1] = (const float*)d_in[1];  ca.dst[1] = xk;
  ca.src[2] = (const float*)d_in[2];  ca.dst[2] = xv;
  ca.src[3] = (const float*)d_in[4];  ca.dst[3] = wq;
  ca.src[4] = (const float*)d_in[6];  ca.dst[4] = wk;
  ca.src[5] = (const float*)d_in[8];  ca.dst[5] = wv;
  ca.src[6] = (const float*)d_in[10]; ca.dst[6] = wo;
  convert_kernel<<<dim3(4096), dim3(256), 0, stream>>>(ca);

  QkvArgs qa;
  qa.A[0] = xq; qa.W[0] = wq; qa.bias[0] = (const float*)d_in[5]; qa.out[0] = Qp;
  qa.A[1] = xk; qa.W[1] = wk; qa.bias[1] = (const float*)d_in[7]; qa.out[1] = Kp;
  qa.A[2] = xv; qa.W[2] = wv; qa.bias[2] = (const float*)d_in[9]; qa.out[2] = Vt;
  qa.scale[0] = 0.125f * 1.44269504089f;  // fold 1/sqrt(dk) * log2(e) into Q
  qa.scale[1] = 1.0f;
  qa.scale[2] = 1.0f;
  gemm_qkv_kernel<<<dim3(8, 32, 3), dim3(256), 0, stream>>>(qa);

  attn_kernel<<<dim3(512), dim3(256), 0, stream>>>(Qp, Kp, Vt, O);

  gemm_out_kernel<<<dim3(8, 64, 1), dim3(256), 0, stream>>>(
      O, wo, (const float*)d_in[11], (float*)d_out);
}